// Round 5
// baseline (537.867 us; speedup 1.0000x reference)
//
#include <hip/hip_runtime.h>
#include <hip/hip_bf16.h>
#include <math.h>

using u16 = unsigned short;
using u32 = unsigned int;

typedef __attribute__((ext_vector_type(8))) short s16x8;
typedef __attribute__((ext_vector_type(4))) float f32x4;

#define B_  4
#define L_  8192
#define D_  512
#define H_  8
#define G_  4

// ---------- helpers ----------
__device__ __forceinline__ float bf2f(u16 u) {
    u32 x = ((u32)u) << 16;
    return __uint_as_float(x);
}
__device__ __forceinline__ u16 f2bf(float f) {  // round-to-nearest-even
    u32 x = __float_as_uint(f);
    u32 lsb = (x >> 16) & 1u;
    x += 0x7FFFu + lsb;
    return (u16)(x >> 16);
}

// ---------- cast fp32 -> bf16 (vectorized x4) ----------
__global__ __launch_bounds__(256) void cast_f32_bf16(const float* __restrict__ src,
                                                     u16* __restrict__ dst, int n4) {
    int i = blockIdx.x * 256 + threadIdx.x;
    if (i >= n4) return;
    float4 v = ((const float4*)src)[i];
    ushort4 o;
    o.x = f2bf(v.x); o.y = f2bf(v.y); o.z = f2bf(v.z); o.w = f2bf(v.w);
    ((ushort4*)dst)[i] = o;
}

// ---------- compose conv1(128x128x5) + conv2(1x128x1) -> Weff[cin*5+dk], beff, b2 ----------
__global__ __launch_bounds__(128) void build_weff(const float* __restrict__ W1,
                                                  const float* __restrict__ b1,
                                                  const float* __restrict__ W2,
                                                  const float* __restrict__ b2,
                                                  float* __restrict__ weff) {
    int idx = blockIdx.x * 128 + threadIdx.x;
    if (idx < 640) {
        int cin = idx / 5, dk = idx % 5;
        float acc = 0.f;
        for (int c = 0; c < 128; ++c) acc += W2[c] * W1[(c * 128 + cin) * 5 + dk];
        weff[idx] = acc;
    } else if (idx == 640) {
        float s = b2[0];
        for (int c = 0; c < 128; ++c) s += W2[c] * b1[c];
        weff[640] = s;              // composed bias (t>=2)
    } else if (idx == 641) {
        weff[641] = b2[0];          // conv2-pad-only bias (t<2)
    }
}

// ---------- fused offset conv + tanh + grid_sample position precompute ----------
__global__ __launch_bounds__(256) void offsets_kernel(const u16* __restrict__ qT,
                                                      const float* __restrict__ weff,
                                                      int* __restrict__ p0o,
                                                      float* __restrict__ w1o) {
    __shared__ u16 qs[128 * 72];   // 128 ch x 72 l (l from t0-8), 18.4 KB
    __shared__ float wf[642];
    __shared__ float red[4][64];
    const int tid = threadIdx.x;
    const int t0 = blockIdx.x * 64;
    const int bg = blockIdx.y;
    const int b = bg >> 2, g = bg & 3;
    for (int i = tid; i < 642; i += 256) wf[i] = weff[i];
    for (int i = tid; i < 128 * 9; i += 256) {
        const int ch = i / 9, seg = i - ch * 9;
        const int l = t0 - 8 + seg * 8;
        s16x8 val = {0, 0, 0, 0, 0, 0, 0, 0};
        if (l >= 0)
            val = *(const s16x8*)(qT + (size_t)(b * D_ + g * 128 + ch) * L_ + l);
        *(s16x8*)(qs + ch * 72 + seg * 8) = val;
    }
    __syncthreads();
    const int w = tid >> 6, lane = tid & 63;
    float acc = 0.f;
    for (int c = 0; c < 32; ++c) {
        const int ch = w * 32 + c;
        const u16* row = qs + ch * 72 + lane + 4;   // lc = (t-t0)+4+dk
        const float* wr = wf + ch * 5;
        #pragma unroll
        for (int dk = 0; dk < 5; ++dk) acc += wr[dk] * bf2f(row[dk]);
    }
    red[w][lane] = acc;
    __syncthreads();
    if (w == 0) {
        const float s = red[0][lane] + red[1][lane] + red[2][lane] + red[3][lane];
        const int t = t0 + lane;
        const float o2 = (t >= 2) ? (s + wf[640]) : wf[641];
        const double offv = tanh((double)o2) * 5.0;
        const double vg  = (double)t + offv;
        const double gg  = 2.0 * vg / 8195.0 - 1.0;          // n-1 = L+3 = 8195
        const double pos = ((gg + 1.0) * 8192.0 - 1.0) * 0.5;
        const double p0d = floor(pos);
        p0o[(size_t)bg * L_ + t] = (int)p0d;
        w1o[(size_t)bg * L_ + t] = (float)(pos - p0d);
    }
}

// ---------- bilinear gather: xs[b,t,d] (bf16), 4 d-channels per thread ----------
__global__ __launch_bounds__(256) void sample_kernel(const float* __restrict__ x,
                                                     const int* __restrict__ p0i,
                                                     const float* __restrict__ w1f,
                                                     u16* __restrict__ xs) {
    const size_t idx4 = (size_t)blockIdx.x * 256 + threadIdx.x;   // B*L*D/4
    const int d4 = (int)(idx4 & 127);           // 4-channel group
    const int t = (int)((idx4 >> 7) & 8191);
    const int b = (int)(idx4 >> 20);
    const int g = d4 >> 5;
    const size_t og = (size_t)(b * 4 + g) * L_ + t;
    const int p0 = p0i[og];
    const float w1 = w1f[og];
    const float w0 = 1.f - w1;
    const int p1 = p0 + 1;
    float4 v0 = {0.f, 0.f, 0.f, 0.f}, v1 = {0.f, 0.f, 0.f, 0.f};
    if (p0 >= 0 && p0 < L_) v0 = *(const float4*)(x + ((size_t)b * L_ + p0) * D_ + d4 * 4);
    if (p1 >= 0 && p1 < L_) v1 = *(const float4*)(x + ((size_t)b * L_ + p1) * D_ + d4 * 4);
    ushort4 o;
    o.x = f2bf(v0.x * w0 + v1.x * w1);
    o.y = f2bf(v0.y * w0 + v1.y * w1);
    o.z = f2bf(v0.z * w0 + v1.z * w1);
    o.w = f2bf(v0.w * w0 + v1.w * w1);
    ((ushort4*)xs)[idx4] = o;
}

// ---------- register-direct MFMA GEMM: C[r,c] = sum_d A[r,d]*W[c,d] (+bias[c]) ----------
// MODE 0: TRANSPOSED bf16 out -> out[b*D + c][l]  (for qT / kT)
// MODE 1: row-major bf16 out + rel_bias            (for v)
// MODE 2: row-major fp32 out, W indexed per-batch  (final)
// NO LDS, NO barriers: MFMA fragments are loaded straight from global with
// dwordx4 (the row-major layout IS the fragment layout). 2-stage register
// pipeline, fully unrolled; compiler's fine-grained vmcnt keeps next stage's
// 8 loads in flight under the current 16 MFMAs. Waves free-run.
template <int MODE>
__global__ __launch_bounds__(256) void gemm_kernel(const u16* __restrict__ A,
                                                   const u16* __restrict__ W,
                                                   const float* __restrict__ bias,
                                                   const float* __restrict__ rel,
                                                   void* __restrict__ out) {
    const int tid = threadIdx.x;
    const int wave = tid >> 6, lane = tid & 63;
    const int bid = blockIdx.x;
    const int xcd = bid & 7;
    const int kk_ = bid >> 3;                 // 0..127
    const int r0 = (xcd * 32 + (kk_ >> 2)) * 128;
    const int c0 = (kk_ & 3) * 128;
    const u16* Wb = (MODE == 2) ? (W + (size_t)(r0 >> 13) * D_ * D_) : W;
    const int wm = (wave >> 1) * 64, wn = (wave & 1) * 64;
    const int fm = lane & 15;                 // fragment row
    const int kq = (lane >> 4) * 8;           // k sub-offset

    const u16* gA = A  + (size_t)(r0 + wm + fm) * D_ + kq;
    const u16* gB = Wb + (size_t)(c0 + wn + fm) * D_ + kq;

    f32x4 acc[4][4];
    #pragma unroll
    for (int mi = 0; mi < 4; ++mi)
        #pragma unroll
        for (int ni = 0; ni < 4; ++ni) acc[mi][ni] = (f32x4){0.f, 0.f, 0.f, 0.f};

    s16x8 a[2][4], b[2][4];
    #pragma unroll
    for (int mi = 0; mi < 4; ++mi) a[0][mi] = *(const s16x8*)(gA + mi * 16 * D_);
    #pragma unroll
    for (int ni = 0; ni < 4; ++ni) b[0][ni] = *(const s16x8*)(gB + ni * 16 * D_);

    #pragma unroll
    for (int it = 0; it < 16; ++it) {
        const int cur = it & 1, nxt = cur ^ 1;
        if (it < 15) {
            const int k1 = (it + 1) * 32;
            #pragma unroll
            for (int mi = 0; mi < 4; ++mi) a[nxt][mi] = *(const s16x8*)(gA + mi * 16 * D_ + k1);
            #pragma unroll
            for (int ni = 0; ni < 4; ++ni) b[nxt][ni] = *(const s16x8*)(gB + ni * 16 * D_ + k1);
        }
        #pragma unroll
        for (int mi = 0; mi < 4; ++mi)
            #pragma unroll
            for (int ni = 0; ni < 4; ++ni)
                acc[mi][ni] = __builtin_amdgcn_mfma_f32_16x16x32_bf16(a[cur][mi], b[cur][ni], acc[mi][ni], 0, 0, 0);
    }

    // epilogue: D layout col = lane&15, row = (lane>>4)*4 + reg
    const int fn = lane & 15;
    const int q4 = (lane >> 4) * 4;
    #pragma unroll
    for (int mi = 0; mi < 4; ++mi) {
        #pragma unroll
        for (int ni = 0; ni < 4; ++ni) {
            const int c = c0 + wn + ni * 16 + fn;
            const float bsum = bias[c];
            if (MODE == 0) {
                const int r_ = r0 + wm + mi * 16 + q4;   // 4 consecutive rows
                const int bb = r_ >> 13;                  // batch
                const int l  = r_ & (L_ - 1);
                ushort4 o;
                o.x = f2bf(acc[mi][ni][0] + bsum);
                o.y = f2bf(acc[mi][ni][1] + bsum);
                o.z = f2bf(acc[mi][ni][2] + bsum);
                o.w = f2bf(acc[mi][ni][3] + bsum);
                *(ushort4*)((u16*)out + (size_t)(bb * D_ + c) * L_ + l) = o;
            } else if (MODE == 1) {
                const int r_ = r0 + wm + mi * 16 + q4;
                const int l  = r_ & (L_ - 1);
                const float4 rl = *(const float4*)(rel + (size_t)c * L_ + l);
                ((u16*)out)[(size_t)(r_ + 0) * D_ + c] = f2bf(acc[mi][ni][0] + bsum + rl.x);
                ((u16*)out)[(size_t)(r_ + 1) * D_ + c] = f2bf(acc[mi][ni][1] + bsum + rl.y);
                ((u16*)out)[(size_t)(r_ + 2) * D_ + c] = f2bf(acc[mi][ni][2] + bsum + rl.z);
                ((u16*)out)[(size_t)(r_ + 3) * D_ + c] = f2bf(acc[mi][ni][3] + bsum + rl.w);
            } else {
                #pragma unroll
                for (int rg = 0; rg < 4; ++rg) {
                    const int r = r0 + wm + mi * 16 + q4 + rg;
                    ((float*)out)[(size_t)r * D_ + c] = acc[mi][ni][rg] + bsum;
                }
            }
        }
    }
}

// ---------- channel-attention scores via MFMA, split-K partials ----------
__global__ __launch_bounds__(256) void scores_partial(const u16* __restrict__ qT,
                                                      const u16* __restrict__ kT,
                                                      float* __restrict__ part) {
    __shared__ u16 qs[64 * 136];   // 64 ch x 128 l, stride 136 (16B-aligned, bank-even)
    __shared__ u16 ks[64 * 136];
    const int chunk = blockIdx.x;   // 0..15, 512 l each
    const int bh = blockIdx.y;      // 0..31
    const int b = bh >> 3, h = bh & 7;
    const int tid = threadIdx.x;
    const int wave = tid >> 6, lane = tid & 63;
    const int wr = (wave >> 1) * 32;   // output row block (q channel)
    const int wc = (wave & 1) * 32;    // output col block (k channel)
    f32x4 acc[2][2];
    #pragma unroll
    for (int mi = 0; mi < 2; ++mi)
        #pragma unroll
        for (int ni = 0; ni < 2; ++ni) acc[mi][ni] = (f32x4){0.f, 0.f, 0.f, 0.f};
    const size_t base = (size_t)(b * D_ + h * 64) * L_;
    const int m = lane & 15, q = lane >> 4;
    for (int iter = 0; iter < 4; ++iter) {
        const int l0 = chunk * 512 + iter * 128;
        __syncthreads();
        for (int i = tid; i < 1024; i += 256) {
            const int lb = i & 15, ch = i >> 4;
            const size_t gidx = base + (size_t)ch * L_ + l0 + lb * 8;
            *(s16x8*)(qs + ch * 136 + lb * 8) = *(const s16x8*)(qT + gidx);
            *(s16x8*)(ks + ch * 136 + lb * 8) = *(const s16x8*)(kT + gidx);
        }
        __syncthreads();
        #pragma unroll
        for (int kst = 0; kst < 4; ++kst) {
            const int kk = kst * 32 + q * 8;
            s16x8 af[2], bfr[2];
            af[0]  = *(const s16x8*)(qs + (wr + m) * 136 + kk);
            af[1]  = *(const s16x8*)(qs + (wr + 16 + m) * 136 + kk);
            bfr[0] = *(const s16x8*)(ks + (wc + m) * 136 + kk);
            bfr[1] = *(const s16x8*)(ks + (wc + 16 + m) * 136 + kk);
            #pragma unroll
            for (int mi = 0; mi < 2; ++mi)
                #pragma unroll
                for (int ni = 0; ni < 2; ++ni)
                    acc[mi][ni] = __builtin_amdgcn_mfma_f32_16x16x32_bf16(af[mi], bfr[ni], acc[mi][ni], 0, 0, 0);
        }
    }
    float* dst = part + (size_t)(bh * 16 + chunk) * 4096;
    const int q4 = (lane >> 4) * 4;
    #pragma unroll
    for (int mi = 0; mi < 2; ++mi) {
        #pragma unroll
        for (int ni = 0; ni < 2; ++ni) {
            const int j = wc + ni * 16 + m;
            #pragma unroll
            for (int rg = 0; rg < 4; ++rg) {
                const int i = wr + mi * 16 + q4 + rg;
                dst[i * 64 + j] = acc[mi][ni][rg];
            }
        }
    }
}

// ---------- sum partials, scale, softmax over last dim ----------
__global__ __launch_bounds__(256) void softmax_kernel(const float* __restrict__ part,
                                                      float* __restrict__ attn) {
    const int tid = threadIdx.x;
    const int wave = tid >> 6, lane = tid & 63;
    const int row = blockIdx.x * 4 + wave;   // (b*H+h)*64 + i, 2048 total
    const int bh = row >> 6, i = row & 63;
    float s = 0.f;
    #pragma unroll
    for (int c = 0; c < 16; ++c) s += part[((size_t)(bh * 16 + c)) * 4096 + i * 64 + lane];
    s *= 0.04419417382415922f;               // 512^-0.5
    float m = s;
    for (int off = 32; off > 0; off >>= 1) m = fmaxf(m, __shfl_xor(m, off));
    float e = expf(s - m);
    float sum = e;
    for (int off = 32; off > 0; off >>= 1) sum += __shfl_xor(sum, off);
    attn[(size_t)bh * 4096 + i * 64 + lane] = e / sum;
}

// ---------- M[b] = Wout * blockdiag(attn[b]) : folds attn-apply + out-proj ----------
__global__ __launch_bounds__(256) void build_M(const float* __restrict__ Wout,
                                               const float* __restrict__ attn,
                                               u16* __restrict__ M) {
    const int idx = blockIdx.x * 256 + threadIdx.x;   // b*512*512 + o*512 + col
    const int col = idx & 511;
    const int o = (idx >> 9) & 511;
    const int b = idx >> 18;
    const int h = col >> 6, j = col & 63;
    const float* wr = Wout + o * 512 + h * 64;
    const float* ar = attn + (size_t)(b * H_ + h) * 4096 + j;
    float s = 0.f;
    #pragma unroll 8
    for (int i = 0; i < 64; ++i) s += wr[i] * ar[i * 64];
    M[idx] = f2bf(s);
}

extern "C" void kernel_launch(void* const* d_in, const int* in_sizes, int n_in,
                              void* d_out, int out_size, void* d_ws, size_t ws_size,
                              hipStream_t stream) {
    const float* x    = (const float*)d_in[0];
    const float* Wq   = (const float*)d_in[1];
    const float* bq   = (const float*)d_in[2];
    const float* Wk   = (const float*)d_in[3];
    const float* bk   = (const float*)d_in[4];
    const float* Wv   = (const float*)d_in[5];
    const float* bv   = (const float*)d_in[6];
    const float* Wo1  = (const float*)d_in[7];
    const float* bo1  = (const float*)d_in[8];
    const float* Wo2  = (const float*)d_in[9];
    const float* bo2  = (const float*)d_in[10];
    const float* rel  = (const float*)d_in[11];
    const float* Wout = (const float*)d_in[12];
    const float* bout = (const float*)d_in[13];

    char* ws = (char*)d_ws;
    const size_t MB = 1024ull * 1024ull;
    u16*   x_bf  = (u16*)(ws);                 // 32 MB; reused as xs after gemm_q
    u16*   qT    = (u16*)(ws + 32 * MB);       // 32 MB, [b*D+ch][l]
    u16*   kT    = (u16*)(ws + 64 * MB);       // 32 MB, [b*D+ch][l]
    u16*   v_bf  = (u16*)(ws + 96 * MB);       // 32 MB, row-major
    u16*   wq_bf = (u16*)(ws + 128 * MB);      // 512 KB each
    u16*   wk_bf = wq_bf + 262144;
    u16*   wv_bf = wk_bf + 262144;
    float* weff  = (float*)(ws + 130 * MB);                   // 642 floats
    int*   p0i   = (int*)(ws + 130 * MB + 65536);             // 512 KB
    float* w1f   = (float*)((char*)p0i + 524288);             // 512 KB
    float* part  = (float*)((char*)w1f + 524288);             // 8 MB (16 chunks)
    float* attn  = (float*)((char*)part + 8 * MB);            // 512 KB
    u16*   M_bf  = (u16*)((char*)attn + 524288);              // 2 MB

    // 1. casts
    cast_f32_bf16<<<16384, 256, 0, stream>>>(x, x_bf, 4194304);
    cast_f32_bf16<<<256, 256, 0, stream>>>(Wq, wq_bf, 65536);
    cast_f32_bf16<<<256, 256, 0, stream>>>(Wk, wk_bf, 65536);
    cast_f32_bf16<<<256, 256, 0, stream>>>(Wv, wv_bf, 65536);
    // 2. compose convs
    build_weff<<<6, 128, 0, stream>>>(Wo1, bo1, Wo2, bo2, weff);
    // 3. q = x @ Wq^T  (stored transposed)
    gemm_kernel<0><<<1024, 256, 0, stream>>>(x_bf, wq_bf, bq, nullptr, (void*)qT);
    // 4. offsets -> sampling positions (reads qT)
    offsets_kernel<<<dim3(128, 16), 256, 0, stream>>>(qT, weff, p0i, w1f);
    // 5. bilinear sample (xs overwrites x_bf region; x_bf dead after gemm_q)
    sample_kernel<<<16384, 256, 0, stream>>>(x, p0i, w1f, x_bf);
    // 6. k (transposed), v (row-major + rel)
    gemm_kernel<0><<<1024, 256, 0, stream>>>(x_bf, wk_bf, bk, nullptr, (void*)kT);
    gemm_kernel<1><<<1024, 256, 0, stream>>>(x_bf, wv_bf, bv, rel, (void*)v_bf);
    // 7. scores (MFMA) + softmax
    scores_partial<<<dim3(16, 32), 256, 0, stream>>>(qT, kT, part);
    softmax_kernel<<<512, 256, 0, stream>>>(part, attn);
    // 8. fold attn into output projection
    build_M<<<4096, 256, 0, stream>>>(Wout, attn, M_bf);
    // 9. final: out = v @ M[b]^T + bout  (fp32 out)
    gemm_kernel<2><<<1024, 256, 0, stream>>>(v_bf, M_bf, bout, nullptr, d_out);
}

// Round 6
// 403.041 us; speedup vs baseline: 1.3345x; 1.3345x over previous
//
#include <hip/hip_runtime.h>
#include <hip/hip_bf16.h>
#include <math.h>

using u16 = unsigned short;
using u32 = unsigned int;

typedef __attribute__((ext_vector_type(8))) short s16x8;
typedef __attribute__((ext_vector_type(4))) float f32x4;

#define B_  4
#define L_  8192
#define D_  512
#define H_  8
#define G_  4

// ---------- helpers ----------
__device__ __forceinline__ float bf2f(u16 u) {
    u32 x = ((u32)u) << 16;
    return __uint_as_float(x);
}
__device__ __forceinline__ u16 f2bf(float f) {  // round-to-nearest-even
    u32 x = __float_as_uint(f);
    u32 lsb = (x >> 16) & 1u;
    x += 0x7FFFu + lsb;
    return (u16)(x >> 16);
}
__device__ __forceinline__ void async16(const void* g, void* l) {
    __builtin_amdgcn_global_load_lds((const __attribute__((address_space(1))) u32*)g,
                                     (__attribute__((address_space(3))) u32*)l, 16, 0, 0);
}
// s_waitcnt immediates (gfx9): vmcnt low4 bits[3:0], high2 bits[15:14]; exp [6:4]; lgkm [11:8]
#define WAIT_VM16  0x4F70
#define WAIT_VM8   0x0F78
#define WAIT_VM0   0x0F70
#define WAIT_LGKM0 0xC07F

// ---------- cast fp32 -> bf16 row-major (for x) ----------
__global__ __launch_bounds__(256) void cast_f32_bf16(const float* __restrict__ src,
                                                     u16* __restrict__ dst, int n4) {
    int i = blockIdx.x * 256 + threadIdx.x;
    if (i >= n4) return;
    float4 v = ((const float4*)src)[i];
    ushort4 o;
    o.x = f2bf(v.x); o.y = f2bf(v.y); o.z = f2bf(v.z); o.w = f2bf(v.w);
    ((ushort4*)dst)[i] = o;
}

// ---------- pack a 512x512 f32 weight into MFMA B-fragment order (bf16) ----------
// pack[((cb*16+kc)*64 + lane)*8 + j] = W[cb*16 + (lane&15)][kc*32 + (lane>>4)*8 + j]
__global__ __launch_bounds__(256) void pack_weight(const float* __restrict__ W0,
                                                   const float* __restrict__ W1,
                                                   const float* __restrict__ W2,
                                                   u16* __restrict__ P0,
                                                   u16* __restrict__ P1,
                                                   u16* __restrict__ P2) {
    const int g = blockIdx.x * 4 + (threadIdx.x >> 6);   // 0..511 = cb*16+kc
    const int lane = threadIdx.x & 63;
    const int cb = g >> 4, kc = g & 15;
    const int q = lane >> 4, fm = lane & 15;
    const float* W = (blockIdx.y == 0) ? W0 : (blockIdx.y == 1) ? W1 : W2;
    u16* P = (blockIdx.y == 0) ? P0 : (blockIdx.y == 1) ? P1 : P2;
    const float* src = W + (size_t)(cb * 16 + fm) * 512 + kc * 32 + q * 8;
    float4 a = *(const float4*)src;
    float4 b = *(const float4*)(src + 4);
    ushort4 o0, o1;
    o0.x = f2bf(a.x); o0.y = f2bf(a.y); o0.z = f2bf(a.z); o0.w = f2bf(a.w);
    o1.x = f2bf(b.x); o1.y = f2bf(b.y); o1.z = f2bf(b.z); o1.w = f2bf(b.w);
    u16* dst = P + (size_t)g * 512 + lane * 8;
    *(ushort4*)dst = o0;
    *(ushort4*)(dst + 4) = o1;
}

// ---------- compose conv1(128x128x5) + conv2(1x128x1) -> Weff ----------
__global__ __launch_bounds__(128) void build_weff(const float* __restrict__ W1,
                                                  const float* __restrict__ b1,
                                                  const float* __restrict__ W2,
                                                  const float* __restrict__ b2,
                                                  float* __restrict__ weff) {
    int idx = blockIdx.x * 128 + threadIdx.x;
    if (idx < 640) {
        int cin = idx / 5, dk = idx % 5;
        float acc = 0.f;
        for (int c = 0; c < 128; ++c) acc += W2[c] * W1[(c * 128 + cin) * 5 + dk];
        weff[idx] = acc;
    } else if (idx == 640) {
        float s = b2[0];
        for (int c = 0; c < 128; ++c) s += W2[c] * b1[c];
        weff[640] = s;              // composed bias (t>=2)
    } else if (idx == 641) {
        weff[641] = b2[0];          // conv2-pad-only bias (t<2)
    }
}

// ---------- fused offset conv + tanh + grid_sample position precompute ----------
__global__ __launch_bounds__(256) void offsets_kernel(const u16* __restrict__ qT,
                                                      const float* __restrict__ weff,
                                                      int* __restrict__ p0o,
                                                      float* __restrict__ w1o) {
    __shared__ u16 qs[128 * 72];   // 128 ch x 72 l (l from t0-8), 18.4 KB
    __shared__ float wf[642];
    __shared__ float red[4][64];
    const int tid = threadIdx.x;
    const int t0 = blockIdx.x * 64;
    const int bg = blockIdx.y;
    const int b = bg >> 2, g = bg & 3;
    for (int i = tid; i < 642; i += 256) wf[i] = weff[i];
    for (int i = tid; i < 128 * 9; i += 256) {
        const int ch = i / 9, seg = i - ch * 9;
        const int l = t0 - 8 + seg * 8;
        s16x8 val = {0, 0, 0, 0, 0, 0, 0, 0};
        if (l >= 0)
            val = *(const s16x8*)(qT + (size_t)(b * D_ + g * 128 + ch) * L_ + l);
        *(s16x8*)(qs + ch * 72 + seg * 8) = val;
    }
    __syncthreads();
    const int w = tid >> 6, lane = tid & 63;
    float acc = 0.f;
    for (int c = 0; c < 32; ++c) {
        const int ch = w * 32 + c;
        const u16* row = qs + ch * 72 + lane + 4;   // lc = (t-t0)+4+dk
        const float* wr = wf + ch * 5;
        #pragma unroll
        for (int dk = 0; dk < 5; ++dk) acc += wr[dk] * bf2f(row[dk]);
    }
    red[w][lane] = acc;
    __syncthreads();
    if (w == 0) {
        const float s = red[0][lane] + red[1][lane] + red[2][lane] + red[3][lane];
        const int t = t0 + lane;
        const float o2 = (t >= 2) ? (s + wf[640]) : wf[641];
        const double offv = tanh((double)o2) * 5.0;
        const double vg  = (double)t + offv;
        const double gg  = 2.0 * vg / 8195.0 - 1.0;          // n-1 = L+3 = 8195
        const double pos = ((gg + 1.0) * 8192.0 - 1.0) * 0.5;
        const double p0d = floor(pos);
        p0o[(size_t)bg * L_ + t] = (int)p0d;
        w1o[(size_t)bg * L_ + t] = (float)(pos - p0d);
    }
}

// ---------- bilinear gather: xs[b,t,d] (bf16), 4 d-channels per thread ----------
__global__ __launch_bounds__(256) void sample_kernel(const float* __restrict__ x,
                                                     const int* __restrict__ p0i,
                                                     const float* __restrict__ w1f,
                                                     u16* __restrict__ xs) {
    const size_t idx4 = (size_t)blockIdx.x * 256 + threadIdx.x;   // B*L*D/4
    const int d4 = (int)(idx4 & 127);           // 4-channel group
    const int t = (int)((idx4 >> 7) & 8191);
    const int b = (int)(idx4 >> 20);
    const int g = d4 >> 5;
    const size_t og = (size_t)(b * 4 + g) * L_ + t;
    const int p0 = p0i[og];
    const float w1 = w1f[og];
    const float w0 = 1.f - w1;
    const int p1 = p0 + 1;
    float4 v0 = {0.f, 0.f, 0.f, 0.f}, v1 = {0.f, 0.f, 0.f, 0.f};
    if (p0 >= 0 && p0 < L_) v0 = *(const float4*)(x + ((size_t)b * L_ + p0) * D_ + d4 * 4);
    if (p1 >= 0 && p1 < L_) v1 = *(const float4*)(x + ((size_t)b * L_ + p1) * D_ + d4 * 4);
    ushort4 o;
    o.x = f2bf(v0.x * w0 + v1.x * w1);
    o.y = f2bf(v0.y * w0 + v1.y * w1);
    o.z = f2bf(v0.z * w0 + v1.z * w1);
    o.w = f2bf(v0.w * w0 + v1.w * w1);
    ((ushort4*)xs)[idx4] = o;
}

// ---------- MFMA GEMM, A wave-private LDS (3-deep), B direct from packed weights ----
// MODE 0: q    -> transposed bf16 out (qT)
// MODE 1: k|v  -> sel=0: transposed bf16 (kT); sel=1: row-major bf16 + rel (v). grid 2x.
// MODE 2: final-> row-major fp32 out, P indexed per-batch
template <int MODE>
__global__ __launch_bounds__(256) void gemm_kernel(const u16* __restrict__ A,
                                                   const u16* __restrict__ P0,
                                                   const u16* __restrict__ P1,
                                                   const float* __restrict__ bias0,
                                                   const float* __restrict__ bias1,
                                                   const float* __restrict__ rel,
                                                   void* __restrict__ out0,
                                                   void* __restrict__ out1) {
    __shared__ short lds[4][3][2048];   // per-wave A triple-buffer = 48 KB
    const int tid = threadIdx.x;
    const int wave = tid >> 6, lane = tid & 63;
    const int bid = blockIdx.x;
    const int xcd = bid & 7;
    const int kk_ = bid >> 3;
    int r0, c0, sel;
    if (MODE == 1) { r0 = (xcd * 32 + (kk_ >> 3)) * 128; sel = (kk_ >> 2) & 1; c0 = (kk_ & 3) * 128; }
    else           { r0 = (xcd * 32 + (kk_ >> 2)) * 128; sel = 0;              c0 = (kk_ & 3) * 128; }
    const u16* P = (MODE == 1 && sel) ? P1 : P0;
    if (MODE == 2) P += (size_t)(r0 >> 13) * 262144;       // per-batch packed M
    const float* bias = (MODE == 1 && sel) ? bias1 : bias0;
    void* out = (MODE == 1 && sel) ? out1 : out0;

    const int wm = (wave >> 1) * 64, wn = (wave & 1) * 64;
    const int srow = lane >> 2;
    const int scol = ((lane & 3) ^ ((srow >> 1) & 3)) * 8;   // XOR-swizzled 16B block
    const u16* gA = A + (size_t)(r0 + wm) * D_ + scol;
    short* bufA[3] = { &lds[wave][0][0], &lds[wave][1][0], &lds[wave][2][0] };
    const int cbase = (c0 + wn) >> 4;

    f32x4 acc[4][4];
    #pragma unroll
    for (int mi = 0; mi < 4; ++mi)
        #pragma unroll
        for (int ni = 0; ni < 4; ++ni) acc[mi][ni] = (f32x4){0.f, 0.f, 0.f, 0.f};

    const int fm = lane & 15;
    const int sblk = ((lane >> 4) ^ ((fm >> 1) & 3)) * 8;    // inverse swizzle

    s16x8 bfrag[3][4];

    auto issueA = [&](int slot, int it) {
        const int k0 = it * 32;
        #pragma unroll
        for (int j = 0; j < 4; ++j)
            async16(gA + (size_t)(j * 16 + srow) * D_ + k0, bufA[slot] + j * 512);
    };
    auto issueB = [&](int slot, int it) {
        #pragma unroll
        for (int ni = 0; ni < 4; ++ni)
            bfrag[slot][ni] = *(const s16x8*)(P + ((size_t)((cbase + ni) * 16 + it) * 64 + lane) * 8);
    };

    issueA(0, 0); issueB(0, 0);
    issueA(1, 1); issueB(1, 1);
    issueA(2, 2); issueB(2, 2);

    #pragma unroll
    for (int it = 0; it < 16; ++it) {
        const int slot = it % 3;
        if (it < 14)       __builtin_amdgcn_s_waitcnt(WAIT_VM16);
        else if (it == 14) __builtin_amdgcn_s_waitcnt(WAIT_VM8);
        else               __builtin_amdgcn_s_waitcnt(WAIT_VM0);
        __builtin_amdgcn_sched_barrier(0);
        s16x8 af[4];
        #pragma unroll
        for (int mi = 0; mi < 4; ++mi)
            af[mi] = *(const s16x8*)(bufA[slot] + mi * 512 + fm * 32 + sblk);
        __builtin_amdgcn_s_waitcnt(WAIT_LGKM0);              // A frags in regs
        __builtin_amdgcn_sched_barrier(0);                   // pin before DMA reissue
        if (it < 13) issueA(slot, it + 3);
        #pragma unroll
        for (int mi = 0; mi < 4; ++mi)
            #pragma unroll
            for (int ni = 0; ni < 4; ++ni)
                acc[mi][ni] = __builtin_amdgcn_mfma_f32_16x16x32_bf16(af[mi], bfrag[slot][ni], acc[mi][ni], 0, 0, 0);
        if (it < 13) issueB(slot, it + 3);
    }

    // epilogue: D layout col = lane&15, row = (lane>>4)*4 + reg
    const int fn = lane & 15;
    const int q4 = (lane >> 4) * 4;
    const bool transposed = (MODE == 0) || (MODE == 1 && sel == 0);
    #pragma unroll
    for (int mi = 0; mi < 4; ++mi) {
        #pragma unroll
        for (int ni = 0; ni < 4; ++ni) {
            const int c = c0 + wn + ni * 16 + fn;
            const float bsum = bias[c];
            if (MODE == 2) {
                #pragma unroll
                for (int rg = 0; rg < 4; ++rg) {
                    const int r = r0 + wm + mi * 16 + q4 + rg;
                    ((float*)out)[(size_t)r * D_ + c] = acc[mi][ni][rg] + bsum;
                }
            } else if (transposed) {
                const int r_ = r0 + wm + mi * 16 + q4;   // 4 consecutive rows
                const int bb = r_ >> 13;
                const int l  = r_ & (L_ - 1);
                ushort4 o;
                o.x = f2bf(acc[mi][ni][0] + bsum);
                o.y = f2bf(acc[mi][ni][1] + bsum);
                o.z = f2bf(acc[mi][ni][2] + bsum);
                o.w = f2bf(acc[mi][ni][3] + bsum);
                *(ushort4*)((u16*)out + (size_t)(bb * D_ + c) * L_ + l) = o;
            } else {
                const int r_ = r0 + wm + mi * 16 + q4;
                const int l  = r_ & (L_ - 1);
                const float4 rl = *(const float4*)(rel + (size_t)c * L_ + l);
                ((u16*)out)[(size_t)(r_ + 0) * D_ + c] = f2bf(acc[mi][ni][0] + bsum + rl.x);
                ((u16*)out)[(size_t)(r_ + 1) * D_ + c] = f2bf(acc[mi][ni][1] + bsum + rl.y);
                ((u16*)out)[(size_t)(r_ + 2) * D_ + c] = f2bf(acc[mi][ni][2] + bsum + rl.z);
                ((u16*)out)[(size_t)(r_ + 3) * D_ + c] = f2bf(acc[mi][ni][3] + bsum + rl.w);
            }
        }
    }
}

// ---------- channel-attention scores via MFMA, split-K partials ----------
__global__ __launch_bounds__(256) void scores_partial(const u16* __restrict__ qT,
                                                      const u16* __restrict__ kT,
                                                      float* __restrict__ part) {
    __shared__ u16 qs[64 * 136];
    __shared__ u16 ks[64 * 136];
    const int chunk = blockIdx.x;   // 0..15, 512 l each
    const int bh = blockIdx.y;      // 0..31
    const int b = bh >> 3, h = bh & 7;
    const int tid = threadIdx.x;
    const int wave = tid >> 6, lane = tid & 63;
    const int wr = (wave >> 1) * 32;
    const int wc = (wave & 1) * 32;
    f32x4 acc[2][2];
    #pragma unroll
    for (int mi = 0; mi < 2; ++mi)
        #pragma unroll
        for (int ni = 0; ni < 2; ++ni) acc[mi][ni] = (f32x4){0.f, 0.f, 0.f, 0.f};
    const size_t base = (size_t)(b * D_ + h * 64) * L_;
    const int m = lane & 15, q = lane >> 4;
    for (int iter = 0; iter < 4; ++iter) {
        const int l0 = chunk * 512 + iter * 128;
        __syncthreads();
        for (int i = tid; i < 1024; i += 256) {
            const int lb = i & 15, ch = i >> 4;
            const size_t gidx = base + (size_t)ch * L_ + l0 + lb * 8;
            *(s16x8*)(qs + ch * 136 + lb * 8) = *(const s16x8*)(qT + gidx);
            *(s16x8*)(ks + ch * 136 + lb * 8) = *(const s16x8*)(kT + gidx);
        }
        __syncthreads();
        #pragma unroll
        for (int kst = 0; kst < 4; ++kst) {
            const int kk = kst * 32 + q * 8;
            s16x8 af[2], bfr[2];
            af[0]  = *(const s16x8*)(qs + (wr + m) * 136 + kk);
            af[1]  = *(const s16x8*)(qs + (wr + 16 + m) * 136 + kk);
            bfr[0] = *(const s16x8*)(ks + (wc + m) * 136 + kk);
            bfr[1] = *(const s16x8*)(ks + (wc + 16 + m) * 136 + kk);
            #pragma unroll
            for (int mi = 0; mi < 2; ++mi)
                #pragma unroll
                for (int ni = 0; ni < 2; ++ni)
                    acc[mi][ni] = __builtin_amdgcn_mfma_f32_16x16x32_bf16(af[mi], bfr[ni], acc[mi][ni], 0, 0, 0);
        }
    }
    float* dst = part + (size_t)(bh * 16 + chunk) * 4096;
    const int q4 = (lane >> 4) * 4;
    #pragma unroll
    for (int mi = 0; mi < 2; ++mi) {
        #pragma unroll
        for (int ni = 0; ni < 2; ++ni) {
            const int j = wc + ni * 16 + m;
            #pragma unroll
            for (int rg = 0; rg < 4; ++rg) {
                const int i = wr + mi * 16 + q4 + rg;
                dst[i * 64 + j] = acc[mi][ni][rg];
            }
        }
    }
}

// ---------- sum partials, scale, softmax over last dim ----------
__global__ __launch_bounds__(256) void softmax_kernel(const float* __restrict__ part,
                                                      float* __restrict__ attn) {
    const int tid = threadIdx.x;
    const int wave = tid >> 6, lane = tid & 63;
    const int row = blockIdx.x * 4 + wave;
    const int bh = row >> 6, i = row & 63;
    float s = 0.f;
    #pragma unroll
    for (int c = 0; c < 16; ++c) s += part[((size_t)(bh * 16 + c)) * 4096 + i * 64 + lane];
    s *= 0.04419417382415922f;               // 512^-0.5
    float m = s;
    for (int off = 32; off > 0; off >>= 1) m = fmaxf(m, __shfl_xor(m, off));
    float e = expf(s - m);
    float sum = e;
    for (int off = 32; off > 0; off >>= 1) sum += __shfl_xor(sum, off);
    attn[(size_t)bh * 4096 + i * 64 + lane] = e / sum;
}

// ---------- M[b] = Wout * blockdiag(attn[b]) written in packed B-fragment order ----
__global__ __launch_bounds__(256) void build_M(const float* __restrict__ Wout,
                                               const float* __restrict__ attn,
                                               u16* __restrict__ Mpack) {
    const int idx = blockIdx.x * 256 + threadIdx.x;   // b*512*512 + o*512 + col
    const int col = idx & 511;                        // k (v-channel)
    const int o = (idx >> 9) & 511;                   // out-channel (GEMM col c)
    const int b = idx >> 18;
    const int h = col >> 6, j0 = col & 63;
    const float* wr = Wout + o * 512 + h * 64;
    const float* ar = attn + (size_t)(b * H_ + h) * 4096 + j0;
    float s = 0.f;
    #pragma unroll 8
    for (int i = 0; i < 64; ++i) s += wr[i] * ar[i * 64];
    const int cb = o >> 4, fm = o & 15;
    const int kc = col >> 5, q = (col >> 3) & 3, j = col & 7;
    Mpack[(size_t)b * 262144 + ((size_t)(cb * 16 + kc) * 64 + q * 16 + fm) * 8 + j] = f2bf(s);
}

extern "C" void kernel_launch(void* const* d_in, const int* in_sizes, int n_in,
                              void* d_out, int out_size, void* d_ws, size_t ws_size,
                              hipStream_t stream) {
    const float* x    = (const float*)d_in[0];
    const float* Wq   = (const float*)d_in[1];
    const float* bq   = (const float*)d_in[2];
    const float* Wk   = (const float*)d_in[3];
    const float* bk   = (const float*)d_in[4];
    const float* Wv   = (const float*)d_in[5];
    const float* bv   = (const float*)d_in[6];
    const float* Wo1  = (const float*)d_in[7];
    const float* bo1  = (const float*)d_in[8];
    const float* Wo2  = (const float*)d_in[9];
    const float* bo2  = (const float*)d_in[10];
    const float* rel  = (const float*)d_in[11];
    const float* Wout = (const float*)d_in[12];
    const float* bout = (const float*)d_in[13];

    char* ws = (char*)d_ws;
    const size_t MB = 1024ull * 1024ull;
    u16*   x_bf  = (u16*)(ws);                 // 32 MB; reused as xs after gemm_q
    u16*   qT    = (u16*)(ws + 32 * MB);       // 32 MB, [b*D+ch][l]
    u16*   kT    = (u16*)(ws + 64 * MB);       // 32 MB, [b*D+ch][l]
    u16*   v_bf  = (u16*)(ws + 96 * MB);       // 32 MB, row-major
    u16*   Pq    = (u16*)(ws + 128 * MB);      // 512 KB each, packed weights
    u16*   Pk    = Pq + 262144;
    u16*   Pv    = Pk + 262144;
    float* weff  = (float*)(ws + 130 * MB);                   // 642 floats
    int*   p0i   = (int*)(ws + 130 * MB + 65536);             // 512 KB
    float* w1f   = (float*)((char*)p0i + 524288);             // 512 KB
    float* part  = (float*)((char*)w1f + 524288);             // 8 MB (16 chunks)
    float* attn  = (float*)((char*)part + 8 * MB);            // 512 KB
    u16*   Mpack = (u16*)((char*)attn + 524288);              // 2 MB packed per-batch

    // 1. cast x, pack all weights
    cast_f32_bf16<<<16384, 256, 0, stream>>>(x, x_bf, 4194304);
    pack_weight<<<dim3(128, 3), 256, 0, stream>>>(Wq, Wk, Wv, Pq, Pk, Pv);
    // 2. compose convs
    build_weff<<<6, 128, 0, stream>>>(Wo1, bo1, Wo2, bo2, weff);
    // 3. q = x @ Wq^T  (stored transposed)
    gemm_kernel<0><<<1024, 256, 0, stream>>>(x_bf, Pq, nullptr, bq, nullptr, nullptr, (void*)qT, nullptr);
    // 4. offsets -> sampling positions (reads qT)
    offsets_kernel<<<dim3(128, 16), 256, 0, stream>>>(qT, weff, p0i, w1f);
    // 5. bilinear sample (xs overwrites x_bf region; x_bf dead after gemm_q)
    sample_kernel<<<16384, 256, 0, stream>>>(x, p0i, w1f, x_bf);
    // 6. k (transposed) + v (row-major + rel) in ONE dispatch
    gemm_kernel<1><<<2048, 256, 0, stream>>>(x_bf, Pk, Pv, bk, bv, rel, (void*)kT, (void*)v_bf);
    // 7. scores (MFMA) + softmax
    scores_partial<<<dim3(16, 32), 256, 0, stream>>>(qT, kT, part);
    softmax_kernel<<<512, 256, 0, stream>>>(part, attn);
    // 8. fold attn into output projection (packed layout)
    build_M<<<4096, 256, 0, stream>>>(Wout, attn, Mpack);
    // 9. final: out = v @ M[b]^T + bout  (fp32 out)
    gemm_kernel<2><<<1024, 256, 0, stream>>>(v_bf, Mpack, nullptr, bout, nullptr, nullptr, d_out, nullptr);
}